// Round 14
// baseline (379.054 us; speedup 1.0000x reference)
//
#include <hip/hip_runtime.h>
#include <hip/hip_bf16.h>
#include <math.h>

// ---------------- problem constants ----------------
constexpr int NN  = 32768;   // nodes
constexpr int BG  = 64;      // graphs
constexpr int NPG = 512;     // nodes per graph
constexpr int EG  = 524288;  // edges
constexpr int EPG = EG / BG; // 8192 edges per graph
constexpr int HH  = 4;       // heads
constexpr int FH  = 64;      // per-head dim
constexpr int CC  = 256;     // H*Fh
constexpr int FIN = 128;
constexpr int KP1 = 256;     // pool1 k
constexpr int KP2 = 128;     // pool2 k

typedef __attribute__((ext_vector_type(8))) short short8;  // 8 bf16 = 4 VGPRs
typedef __attribute__((ext_vector_type(4))) float f32x4;

__device__ inline float leaky02(float v) { return v > 0.0f ? v : 0.2f * v; }

__device__ inline unsigned short f2bf(float v) {
    __hip_bfloat16 h = __float2bfloat16(v);
    return *(unsigned short*)&h;
}
__device__ inline float bf2f(unsigned short u) {
    __hip_bfloat16 h;
    *(unsigned short*)&h = u;
    return __bfloat162float(h);
}
__device__ inline void split2(float v, unsigned short& hi, unsigned short& lo) {
    hi = f2bf(v);
    lo = f2bf(v - bf2f(hi));
}
__device__ inline void split8(const float* p, short8& hi, short8& lo) {
    const float4 f0 = *(const float4*)p;
    const float4 f1 = *(const float4*)(p + 4);
    unsigned short h, l;
    split2(f0.x, h, l); hi[0] = (short)h; lo[0] = (short)l;
    split2(f0.y, h, l); hi[1] = (short)h; lo[1] = (short)l;
    split2(f0.z, h, l); hi[2] = (short)h; lo[2] = (short)l;
    split2(f0.w, h, l); hi[3] = (short)h; lo[3] = (short)l;
    split2(f1.x, h, l); hi[4] = (short)h; lo[4] = (short)l;
    split2(f1.y, h, l); hi[5] = (short)h; lo[5] = (short)l;
    split2(f1.z, h, l); hi[6] = (short)h; lo[6] = (short)l;
    split2(f1.w, h, l); hi[7] = (short)h; lo[7] = (short)l;
}
__device__ inline float readlane_f(float v, int lane) {
    return __int_as_float(__builtin_amdgcn_readlane(__float_as_int(v), lane));
}

// ---------------- W pack: fp32 -> FRAGMENT-PACKED split bf16 --------------
__global__ __launch_bounds__(256) void conv_wpack(const float* __restrict__ W1,
                                                  const float* __restrict__ W2,
                                                  unsigned short* __restrict__ w1ph,
                                                  unsigned short* __restrict__ w1pl,
                                                  unsigned short* __restrict__ w2ph,
                                                  unsigned short* __restrict__ w2pl) {
    int idx = blockIdx.x * 256 + threadIdx.x;      // 0 .. 12287
    if (idx < 4096) {                              // W1: 16 nt x 4 kg x 64 l
        const int nt = idx >> 8, rem = idx & 255;
        const int kg = rem >> 6, l = rem & 63;
        const int n = nt * 16 + (l & 15);
        const int kb = kg * 32 + (l >> 4) * 8;
        unsigned short h[8], lo[8];
#pragma unroll
        for (int j = 0; j < 8; ++j) split2(W1[(kb + j) * CC + n], h[j], lo[j]);
#pragma unroll
        for (int j = 0; j < 8; ++j) {
            w1ph[(size_t)idx * 8 + j] = h[j];
            w1pl[(size_t)idx * 8 + j] = lo[j];
        }
    } else if (idx < 12288) {                      // W2: 16 nt x 8 kg x 64 l
        const int i2 = idx - 4096;
        const int nt = i2 >> 9, rem = i2 & 511;
        const int kg = rem >> 6, l = rem & 63;
        const int n = nt * 16 + (l & 15);
        const int kb = kg * 32 + (l >> 4) * 8;
        unsigned short h[8], lo[8];
#pragma unroll
        for (int j = 0; j < 8; ++j) split2(W2[(kb + j) * CC + n], h[j], lo[j]);
#pragma unroll
        for (int j = 0; j < 8; ++j) {
            w2ph[(size_t)i2 * 8 + j] = h[j];
            w2pl[(size_t)i2 * 8 + j] = lo[j];
        }
    }
}

// ---------------- MFMA GEMM (layer 2): A = split-bf16 pair ----------------
__global__ __launch_bounds__(256, 4) void gemm_mfma_attn(
        const unsigned short* __restrict__ Ahi, const unsigned short* __restrict__ Alo,
        const unsigned short* __restrict__ Bph, const unsigned short* __restrict__ Bpl,
        float* __restrict__ Cm, int K,
        const float* __restrict__ a_src, const float* __restrict__ a_dst,
        float* __restrict__ es, float* __restrict__ ed) {
    const int t = threadIdx.x;
    const int w = t >> 6;
    const int l = t & 63;
    const int bx   = blockIdx.x;
    const int xcd  = bx & 7;
    const int slot = bx >> 3;
    const int gph  = xcd + ((slot >> 4) << 3);
    const int row0 = gph * NPG + ((slot & 15) << 5);
    const int m = l & 15;
    const int q = l >> 4;
    const int ncol0 = w * 64;
    const int KG = K >> 5;

    const unsigned short* aH0 = Ahi + (size_t)(row0 + m) * K + q * 8;
    const unsigned short* aL0 = Alo + (size_t)(row0 + m) * K + q * 8;
    const unsigned short* aH1 = aH0 + (size_t)16 * K;
    const unsigned short* aL1 = aL0 + (size_t)16 * K;

    f32x4 acc0[4], acc1[4];
#pragma unroll
    for (int c = 0; c < 4; ++c) {
        acc0[c] = (f32x4){0.f, 0.f, 0.f, 0.f};
        acc1[c] = (f32x4){0.f, 0.f, 0.f, 0.f};
    }

    for (int kg = 0; kg < KG; ++kg) {
        const int ko = kg * 32;
        short8 ah0 = *(const short8*)(aH0 + ko);
        short8 al0 = *(const short8*)(aL0 + ko);
        short8 ah1 = *(const short8*)(aH1 + ko);
        short8 al1 = *(const short8*)(aL1 + ko);
#pragma unroll
        for (int c = 0; c < 4; ++c) {
            const int nt = (w << 2) + c;
            const size_t boff = ((size_t)(nt * KG + kg) * 64 + l) * 8;
            short8 bh = *(const short8*)(Bph + boff);
            short8 bl = *(const short8*)(Bpl + boff);
            acc0[c] = __builtin_amdgcn_mfma_f32_16x16x32_bf16(ah0, bh, acc0[c], 0, 0, 0);
            acc0[c] = __builtin_amdgcn_mfma_f32_16x16x32_bf16(ah0, bl, acc0[c], 0, 0, 0);
            acc0[c] = __builtin_amdgcn_mfma_f32_16x16x32_bf16(al0, bh, acc0[c], 0, 0, 0);
            acc1[c] = __builtin_amdgcn_mfma_f32_16x16x32_bf16(ah1, bh, acc1[c], 0, 0, 0);
            acc1[c] = __builtin_amdgcn_mfma_f32_16x16x32_bf16(ah1, bl, acc1[c], 0, 0, 0);
            acc1[c] = __builtin_amdgcn_mfma_f32_16x16x32_bf16(al1, bh, acc1[c], 0, 0, 0);
        }
    }

#pragma unroll
    for (int c = 0; c < 4; ++c)
#pragma unroll
        for (int r = 0; r < 4; ++r) {
            Cm[(size_t)(row0 + q * 4 + r) * CC + ncol0 + c * 16 + m] = acc0[c][r];
            Cm[(size_t)(row0 + 16 + q * 4 + r) * CC + ncol0 + c * 16 + m] = acc1[c][r];
        }

    float asv[4], adv[4];
#pragma unroll
    for (int c = 0; c < 4; ++c) {
        asv[c] = a_src[ncol0 + c * 16 + m];
        adv[c] = a_dst[ncol0 + c * 16 + m];
    }
#pragma unroll
    for (int r = 0; r < 4; ++r) {
        float ps0 = 0.f, pd0 = 0.f, ps1 = 0.f, pd1 = 0.f;
#pragma unroll
        for (int c = 0; c < 4; ++c) {
            ps0 = fmaf(acc0[c][r], asv[c], ps0);
            pd0 = fmaf(acc0[c][r], adv[c], pd0);
            ps1 = fmaf(acc1[c][r], asv[c], ps1);
            pd1 = fmaf(acc1[c][r], adv[c], pd1);
        }
#pragma unroll
        for (int o = 8; o >= 1; o >>= 1) {
            ps0 += __shfl_down(ps0, o, 16);
            pd0 += __shfl_down(pd0, o, 16);
            ps1 += __shfl_down(ps1, o, 16);
            pd1 += __shfl_down(pd1, o, 16);
        }
        if (m == 0) {
            es[(row0 + q * 4 + r) * HH + w] = ps0;
            ed[(row0 + q * 4 + r) * HH + w] = pd0;
            es[(row0 + 16 + q * 4 + r) * HH + w] = ps1;
            ed[(row0 + 16 + q * 4 + r) * HH + w] = pd1;
        }
    }
}

// ---------------- MFMA GEMM (layer 1): A = fp32, split in-register --------
__global__ __launch_bounds__(256, 4) void gemm_mfma_attn_f32(
        const float* __restrict__ Af,
        const unsigned short* __restrict__ Bph, const unsigned short* __restrict__ Bpl,
        float* __restrict__ Cm, int K,
        const float* __restrict__ a_src, const float* __restrict__ a_dst,
        float* __restrict__ es, float* __restrict__ ed) {
    const int t = threadIdx.x;
    const int w = t >> 6;
    const int l = t & 63;
    const int bx   = blockIdx.x;
    const int xcd  = bx & 7;
    const int slot = bx >> 3;
    const int gph  = xcd + ((slot >> 4) << 3);
    const int row0 = gph * NPG + ((slot & 15) << 5);
    const int m = l & 15;
    const int q = l >> 4;
    const int ncol0 = w * 64;
    const int KG = K >> 5;

    const float* aF0 = Af + (size_t)(row0 + m) * K + q * 8;
    const float* aF1 = aF0 + (size_t)16 * K;

    f32x4 acc0[4], acc1[4];
#pragma unroll
    for (int c = 0; c < 4; ++c) {
        acc0[c] = (f32x4){0.f, 0.f, 0.f, 0.f};
        acc1[c] = (f32x4){0.f, 0.f, 0.f, 0.f};
    }

    for (int kg = 0; kg < KG; ++kg) {
        const int ko = kg * 32;
        short8 ah0, al0, ah1, al1;
        split8(aF0 + ko, ah0, al0);
        split8(aF1 + ko, ah1, al1);
#pragma unroll
        for (int c = 0; c < 4; ++c) {
            const int nt = (w << 2) + c;
            const size_t boff = ((size_t)(nt * KG + kg) * 64 + l) * 8;
            short8 bh = *(const short8*)(Bph + boff);
            short8 bl = *(const short8*)(Bpl + boff);
            acc0[c] = __builtin_amdgcn_mfma_f32_16x16x32_bf16(ah0, bh, acc0[c], 0, 0, 0);
            acc0[c] = __builtin_amdgcn_mfma_f32_16x16x32_bf16(ah0, bl, acc0[c], 0, 0, 0);
            acc0[c] = __builtin_amdgcn_mfma_f32_16x16x32_bf16(al0, bh, acc0[c], 0, 0, 0);
            acc1[c] = __builtin_amdgcn_mfma_f32_16x16x32_bf16(ah1, bh, acc1[c], 0, 0, 0);
            acc1[c] = __builtin_amdgcn_mfma_f32_16x16x32_bf16(ah1, bl, acc1[c], 0, 0, 0);
            acc1[c] = __builtin_amdgcn_mfma_f32_16x16x32_bf16(al1, bh, acc1[c], 0, 0, 0);
        }
    }

#pragma unroll
    for (int c = 0; c < 4; ++c)
#pragma unroll
        for (int r = 0; r < 4; ++r) {
            Cm[(size_t)(row0 + q * 4 + r) * CC + ncol0 + c * 16 + m] = acc0[c][r];
            Cm[(size_t)(row0 + 16 + q * 4 + r) * CC + ncol0 + c * 16 + m] = acc1[c][r];
        }

    float asv[4], adv[4];
#pragma unroll
    for (int c = 0; c < 4; ++c) {
        asv[c] = a_src[ncol0 + c * 16 + m];
        adv[c] = a_dst[ncol0 + c * 16 + m];
    }
#pragma unroll
    for (int r = 0; r < 4; ++r) {
        float ps0 = 0.f, pd0 = 0.f, ps1 = 0.f, pd1 = 0.f;
#pragma unroll
        for (int c = 0; c < 4; ++c) {
            ps0 = fmaf(acc0[c][r], asv[c], ps0);
            pd0 = fmaf(acc0[c][r], adv[c], pd0);
            ps1 = fmaf(acc1[c][r], asv[c], ps1);
            pd1 = fmaf(acc1[c][r], adv[c], pd1);
        }
#pragma unroll
        for (int o = 8; o >= 1; o >>= 1) {
            ps0 += __shfl_down(ps0, o, 16);
            pd0 += __shfl_down(pd0, o, 16);
            ps1 += __shfl_down(ps1, o, 16);
            pd1 += __shfl_down(pd1, o, 16);
        }
        if (m == 0) {
            es[(row0 + q * 4 + r) * HH + w] = ps0;
            ed[(row0 + q * 4 + r) * HH + w] = pd0;
            es[(row0 + 16 + q * 4 + r) * HH + w] = ps1;
            ed[(row0 + 16 + q * 4 + r) * HH + w] = pd1;
        }
    }
}

// ---------------- prep: w12 + T = tw2@c1w + bc2 = tb2@c1w ------------------
__global__ __launch_bounds__(256) void prep(const float* __restrict__ tw1,
                                            const float* __restrict__ sw2,
                                            float* __restrict__ w12,
                                            const float* __restrict__ tw2,
                                            const float* __restrict__ c1w,
                                            const float* __restrict__ tb2,
                                            float* __restrict__ T,
                                            float* __restrict__ bc2) {
    const int b = blockIdx.x;
    const int t = threadIdx.x;
    if (b == 0) {
        float s = 0.0f;
        for (int o = 0; o < CC; ++o) s += tw1[t * CC + o] * sw2[o];
        w12[t] = s;
    } else if (b < 65) {
        const int r = (b - 1) * 4 + (t >> 6);
        const int cth = t & 63;
        float s = 0.0f;
        for (int j = 0; j < CC; ++j) s = fmaf(tw2[r * CC + j], c1w[j * 64 + cth], s);
        T[r * 64 + cth] = s;
    } else if (t < 64) {
        float s = 0.0f;
        for (int j = 0; j < CC; ++j) s = fmaf(tb2[j], c1w[j * 64 + t], s);
        bc2[t] = s;
    }
}

// ---------------- fold_W: Wc = tw1@T, bc = tb1@T + bc2 + c1b --------------
__global__ __launch_bounds__(256) void fold_W(const float* __restrict__ tw1,
                                              const float* __restrict__ T,
                                              const float* __restrict__ tb1,
                                              const float* __restrict__ bc2,
                                              const float* __restrict__ c1b,
                                              float* __restrict__ Wc,
                                              float* __restrict__ bc) {
    const int b = blockIdx.x;
    const int t = threadIdx.x;
    if (b < 64) {
        const int r = b * 4 + (t >> 6);
        const int cth = t & 63;
        float s = 0.0f;
        for (int j = 0; j < CC; ++j) s = fmaf(tw1[r * CC + j], T[j * 64 + cth], s);
        Wc[r * 64 + cth] = s;
    } else if (t < 64) {
        float s = 0.0f;
        for (int j = 0; j < CC; ++j) s = fmaf(tb1[j], T[j * 64 + t], s);
        bc[t] = s + bc2[t] + c1b[t];
    }
}

// ---------------- single-kernel CSR build: one block per graph ------------
__global__ __launch_bounds__(1024) void csr_build(const int* __restrict__ src,
                                                  const int* __restrict__ dst,
                                                  int* __restrict__ rowp,
                                                  int* __restrict__ esrc) {
    __shared__ int lcnt[NPG];
    __shared__ int lofs[NPG];
    const int g = blockIdx.x;
    const int t = threadIdx.x;
    const int ebase = g * EPG;
    const int nbase = g * NPG;
    if (t < NPG) lcnt[t] = 0;
    __syncthreads();
    int ds[EPG / 1024];
#pragma unroll
    for (int j = 0; j < EPG / 1024; ++j) {
        ds[j] = dst[ebase + t + 1024 * j] - nbase;
        atomicAdd(&lcnt[ds[j]], 1);
    }
    __syncthreads();
    if (t < NPG) lofs[t] = lcnt[t];
    __syncthreads();
    for (int o = 1; o < NPG; o <<= 1) {
        int v = 0;
        if (t < NPG && t >= o) v = lofs[t - o];
        __syncthreads();
        if (t < NPG) lofs[t] += v;
        __syncthreads();
    }
    if (t < NPG) {
        int ex = lofs[t] - lcnt[t];
        rowp[nbase + t] = ebase + ex;
        lcnt[t] = ex;
    }
    if (g == BG - 1 && t == 0) rowp[NN] = EG;
    __syncthreads();
#pragma unroll
    for (int j = 0; j < EPG / 1024; ++j) {
        int p = atomicAdd(&lcnt[ds[j]], 1);
        esrc[ebase + p] = src[ebase + t + 1024 * j];
    }
}

// ---------------- LDS-resident GAT edge stage -----------------------------
// One block per (graph, channel-quarter=head): z-quarter (128KB) + es/ed/rowp
// staged in LDS; per-node softmax in-wave (edge values in lanes); aggregation
// via conflict-free ds_read_b32. 256 blocks x 1024 thr, 1 block/CU.
// XCD swizzle: graph g -> XCD g&7 (matches gemm producer).
// Layer 1: writes bf16 split (outh/outl). Layer 2: fp32 out + score planes.
__global__ __launch_bounds__(1024, 1) void gat_lds(
        const float* __restrict__ z,
        const int* __restrict__ rowp,
        const int* __restrict__ esrc,
        const float* __restrict__ es,
        const float* __restrict__ ed,
        const float* __restrict__ bias,
        float* __restrict__ outF,
        unsigned short* __restrict__ outh,
        unsigned short* __restrict__ outl,
        const float* __restrict__ sw1,
        const float* __restrict__ w12,
        float* __restrict__ scp1,
        float* __restrict__ scp2) {
    __shared__ float zq[NPG * 64];     // 128 KB
    __shared__ float esq[NPG], edq[NPG];
    __shared__ int   lrp[NPG + 1];
    const int b    = blockIdx.x;          // 0..255
    const int xcd  = b & 7;
    const int slot = b >> 3;              // 0..31
    const int q    = slot & 3;            // quarter = head
    const int gg   = slot >> 2;           // 0..7
    const int g    = xcd + 8 * gg;        // graph (XCD-local)
    const int nbase = g * NPG;
    const int t = threadIdx.x;
    const int w = t >> 6, l = t & 63;

    // ---- stage z-quarter / es / ed / rowp ----
    for (int i = t; i < NPG * 16; i += 1024) {
        const int row = i >> 4, c4 = i & 15;
        float4 v = *(const float4*)(z + (size_t)(nbase + row) * CC + q * 64 + c4 * 4);
        *(float4*)(zq + row * 64 + c4 * 4) = v;
    }
    if (t < NPG) {
        esq[t] = es[(nbase + t) * HH + q];
        edq[t] = ed[(nbase + t) * HH + q];
        lrp[t] = rowp[nbase + t];
    }
    if (t == 0) lrp[NPG] = rowp[nbase + NPG];
    __syncthreads();

    // per-lane constants
    const float bq  = bias[q * 64 + l];
    const float s1c = scp1 ? sw1[q * 64 + l] : 0.0f;
    const float s2c = scp1 ? w12[q * 64 + l] : 0.0f;

    for (int i = 0; i < 32; ++i) {
        const int n = w * 32 + i;
        const int d = nbase + n;
        const int beg = lrp[n];
        const int deg = lrp[n + 1] - beg;
        const float edn = edq[n];
        const float vself = leaky02(esq[n] + edn);
        float acc;

        if (deg <= 64) {
            // ---- in-wave softmax: edge slot = lane ----
            const int esl = esrc[beg + l];           // padded over-read ok
            const int sl  = (l < deg) ? (esl - nbase) : n;
            const float v = (l < deg) ? leaky02(esq[sl] + edn) : -1e30f;
            float vmax = v;
#pragma unroll
            for (int o = 1; o <= 32; o <<= 1) vmax = fmaxf(vmax, __shfl_xor(vmax, o));
            vmax = fmaxf(vmax, vself);
            const float exv = __expf(v - vmax);      // pads -> 0
            float dsum = exv;
#pragma unroll
            for (int o = 1; o <= 32; o <<= 1) dsum += __shfl_xor(dsum, o);
            const float eself = __expf(vself - vmax);
            const float inv = 1.0f / (dsum + eself + 1e-16f);
            const float alpha = exv * inv;           // per-lane (0 on pads)
            acc = (eself * inv) * zq[n * 64 + l];
            // ---- LDS aggregation, 4-edge unrolled ----
            for (int eb = 0; eb < 64; eb += 4) {
                if (eb < deg) {
#pragma unroll
                    for (int e2 = 0; e2 < 4; ++e2) {
                        const int e = eb + e2;
                        const int sn = __builtin_amdgcn_readlane(sl, e);
                        const float a = readlane_f(alpha, e);
                        acc = fmaf(a, zq[sn * 64 + l], acc);
                    }
                }
            }
        } else {
            // ---- generic chunked path (not taken for the fixed input) ----
            float vmax = vself;
            for (int c0 = 0; c0 < deg; c0 += 64) {
                const int nn = deg - c0;
                const int e2 = esrc[beg + c0 + l];
                const int s2 = (l < nn) ? (e2 - nbase) : n;
                float v2 = (l < nn) ? leaky02(esq[s2] + edn) : -1e30f;
#pragma unroll
                for (int o = 1; o <= 32; o <<= 1) v2 = fmaxf(v2, __shfl_xor(v2, o));
                vmax = fmaxf(vmax, v2);
            }
            float dsum = 0.0f;
            for (int c0 = 0; c0 < deg; c0 += 64) {
                const int nn = deg - c0;
                const int e2 = esrc[beg + c0 + l];
                const int s2 = (l < nn) ? (e2 - nbase) : n;
                float ex2 = (l < nn) ? __expf(leaky02(esq[s2] + edn) - vmax) : 0.0f;
#pragma unroll
                for (int o = 1; o <= 32; o <<= 1) ex2 += __shfl_xor(ex2, o);
                dsum += ex2;
            }
            const float eself = __expf(vself - vmax);
            const float inv = 1.0f / (dsum + eself + 1e-16f);
            acc = (eself * inv) * zq[n * 64 + l];
            for (int c0 = 0; c0 < deg; c0 += 64) {
                const int nn = min(64, deg - c0);
                const int e2 = esrc[beg + c0 + l];
                const int s2 = (l < nn) ? (e2 - nbase) : n;
                const float a2 = (l < nn)
                    ? __expf(leaky02(esq[s2] + edn) - vmax) * inv : 0.0f;
                for (int e = 0; e < nn; ++e) {
                    const int sn = __builtin_amdgcn_readlane(s2, e);
                    const float a = readlane_f(a2, e);
                    acc = fmaf(a, zq[sn * 64 + l], acc);
                }
            }
        }

        // ---- epilogue: bias + ELU (+ outputs) ----
        float o = acc + bq;
        o = o > 0.0f ? o : expm1f(o);
        if (outF) outF[(size_t)d * CC + q * 64 + l] = o;
        if (outh) {
            unsigned short uh, ul;
            split2(o, uh, ul);
            outh[(size_t)d * CC + q * 64 + l] = uh;
            outl[(size_t)d * CC + q * 64 + l] = ul;
        }
        if (scp1) {
            float r1 = o * s1c;
            float r2 = o * s2c;
#pragma unroll
            for (int o2 = 1; o2 <= 32; o2 <<= 1) {
                r1 += __shfl_xor(r1, o2);
                r2 += __shfl_xor(r2, o2);
            }
            if (l == 0) {
                scp1[(size_t)q * NN + d] = r1;
                scp2[(size_t)q * NN + d] = r2;
            }
        }
    }
}

// ---------------- top-k1 rank counting, 4 blocks/graph --------------------
// Scores = sum of 4 quarter planes (bias constants dropped: rank-invariant).
__global__ __launch_bounds__(128) void topk_ranks(const float* __restrict__ scp,
                                                  int* __restrict__ sel, int k) {
    __shared__ float s4[NPG];
    const int b = blockIdx.x;
    const int g = b >> 2;
    const int p = b & 3;
    const int t = threadIdx.x;   // 0..127
    for (int j = t; j < NPG; j += 128) {
        const int nd = g * NPG + j;
        s4[j] = scp[nd] + scp[NN + nd] + scp[2 * NN + nd] + scp[3 * NN + nd];
    }
    __syncthreads();
    const int n = p * 128 + t;
    const float my = s4[n];
    int rank = 0;
#pragma unroll 16
    for (int j4 = 0; j4 < NPG / 4; ++j4) {
        const float4 sv = *(const float4*)(s4 + j4 * 4);
        const int jb = j4 * 4;
        rank += (sv.x > my) || (sv.x == my && (jb + 0) < n);
        rank += (sv.y > my) || (sv.y == my && (jb + 1) < n);
        rank += (sv.z > my) || (sv.z == my && (jb + 2) < n);
        rank += (sv.w > my) || (sv.w == my && (jb + 3) < n);
    }
    sel[(size_t)g * NPG + n] = (rank < k);
}

// ---------------- fused top-k2 + masked partial mean, 4 blocks/graph ------
__global__ __launch_bounds__(256) void topk2_mean(const float* __restrict__ scp2,
                                                  const int* __restrict__ sel1,
                                                  const float* __restrict__ feat,
                                                  float* __restrict__ partial) {
    __shared__ float s4[NPG];
    __shared__ int keep[128];
    __shared__ float vbuf[4][CC];
    const int b = blockIdx.x;    // 0..255
    const int g = b >> 2, p = b & 3;
    const int t = threadIdx.x;   // 0..255
    if (t < 128) {
        for (int jj = 0; jj < 4; ++jj) {
            const int j = t + 128 * jj;
            const int nd = g * NPG + j;
            float v = scp2[nd] + scp2[NN + nd] + scp2[2 * NN + nd] + scp2[3 * NN + nd];
            s4[j] = sel1[nd] ? v : -INFINITY;
        }
    }
    __syncthreads();
    if (t < 128) {
        const int n = p * 128 + t;
        const float my = s4[n];
        int rank = 0;
#pragma unroll 16
        for (int j4 = 0; j4 < NPG / 4; ++j4) {
            const float4 sv = *(const float4*)(s4 + j4 * 4);
            const int jb = j4 * 4;
            rank += (sv.x > my) || (sv.x == my && (jb + 0) < n);
            rank += (sv.y > my) || (sv.y == my && (jb + 1) < n);
            rank += (sv.z > my) || (sv.z == my && (jb + 2) < n);
            rank += (sv.w > my) || (sv.w == my && (jb + 3) < n);
        }
        keep[t] = (rank < KP2) && sel1[(size_t)g * NPG + n];
    }
    __syncthreads();
    const int r = t >> 6, c4 = t & 63;
    float4 acc = make_float4(0.f, 0.f, 0.f, 0.f);
    const float4* f4 = (const float4*)(feat + ((size_t)g * NPG + p * 128) * CC);
    for (int j = r; j < 128; j += 4) {
        if (keep[j]) {
            float4 v = f4[j * 64 + c4];
            acc.x += v.x; acc.y += v.y; acc.z += v.z; acc.w += v.w;
        }
    }
    vbuf[r][c4 * 4 + 0] = acc.x;
    vbuf[r][c4 * 4 + 1] = acc.y;
    vbuf[r][c4 * 4 + 2] = acc.z;
    vbuf[r][c4 * 4 + 3] = acc.w;
    __syncthreads();
    partial[(size_t)(g * 4 + p) * CC + t] =
        vbuf[0][t] + vbuf[1][t] + vbuf[2][t] + vbuf[3][t];
}

// ---------------- folded head ----------------
__global__ __launch_bounds__(256) void head_k(const float* __restrict__ partial,
                                              const float* __restrict__ Wc,
                                              const float* __restrict__ bc,
                                              const float* __restrict__ c2w,
                                              const float* __restrict__ c2b,
                                              float* __restrict__ out) {
    __shared__ float v0[CC];
    __shared__ float part[4][64];
    __shared__ float v2[64];
    const int g = blockIdx.x;
    const int i = threadIdx.x;
    float tsum = partial[(size_t)(g * 4 + 0) * CC + i] +
                 partial[(size_t)(g * 4 + 1) * CC + i] +
                 partial[(size_t)(g * 4 + 2) * CC + i] +
                 partial[(size_t)(g * 4 + 3) * CC + i];
    v0[i] = tsum * (1.0f / KP2);
    __syncthreads();
    {
        const int q = i >> 6, cth = i & 63;
        float p = 0.0f;
        for (int j = q * 64; j < q * 64 + 64; ++j)
            p = fmaf(v0[j], Wc[j * 64 + cth], p);
        part[q][cth] = p;
    }
    __syncthreads();
    if (i < 64) {
        float u = bc[i];
#pragma unroll
        for (int q = 0; q < 4; ++q) u += part[q][i];
        v2[i] = fmaxf(u, 0.0f);
    }
    __syncthreads();
    if (i < 2) {
        float o = c2b[i];
        for (int j = 0; j < 64; ++j) o = fmaf(v2[j], c2w[j * 2 + i], o);
        part[0][i] = o;
    }
    __syncthreads();
    if (i == 0) {
        float a = part[0][0], bq = part[0][1];
        float mx = fmaxf(a, bq);
        float lse = mx + logf(expf(a - mx) + expf(bq - mx));
        out[g * 2 + 0] = a - lse;
        out[g * 2 + 1] = bq - lse;
    }
}

// ---------------- launcher ----------------
extern "C" void kernel_launch(void* const* d_in, const int* in_sizes, int n_in,
                              void* d_out, int out_size, void* d_ws, size_t ws_size,
                              hipStream_t stream) {
    const float* x      = (const float*)d_in[0];
    const int*   ei     = (const int*)d_in[1];
    const int*   src    = ei;
    const int*   dst    = ei + EG;
    const float* W1     = (const float*)d_in[3];
    const float* a_src1 = (const float*)d_in[4];
    const float* a_dst1 = (const float*)d_in[5];
    const float* b1     = (const float*)d_in[6];
    const float* W2     = (const float*)d_in[7];
    const float* a_src2 = (const float*)d_in[8];
    const float* a_dst2 = (const float*)d_in[9];
    const float* b2     = (const float*)d_in[10];
    const float* p1_sw  = (const float*)d_in[11];
    const float* p1_tw  = (const float*)d_in[13];
    const float* p1_tb  = (const float*)d_in[14];
    const float* p2_sw  = (const float*)d_in[15];
    const float* p2_tw  = (const float*)d_in[17];
    const float* p2_tb  = (const float*)d_in[18];
    const float* c1w    = (const float*)d_in[19];
    const float* c1b    = (const float*)d_in[20];
    const float* c2w    = (const float*)d_in[21];
    const float* c2b    = (const float*)d_in[22];
    float* out = (float*)d_out;

    // workspace layout
    float* ws = (float*)d_ws;
    float* z = ws;                                      // NN*CC floats
    float* fregion = z + (size_t)NN * CC;               // NN*CC floats
    unsigned short* fhi = (unsigned short*)fregion;     //   phase 1: fhi/flo bf16
    unsigned short* flo = fhi + (size_t)NN * CC;
    float* featF = fregion;                             //   phase 2: fp32 feat (alias)
    float* wsp = fregion + (size_t)NN * CC;
    unsigned short* w1ph = (unsigned short*)wsp;        // 256*128 packed
    unsigned short* w1pl = w1ph + 256 * FIN;
    unsigned short* w2ph = w1pl + 256 * FIN;            // 256*256 packed
    unsigned short* w2pl = w2ph + 256 * CC;
    float* es  = (float*)(w2pl + 256 * CC);             // N*H
    float* ed  = es + NN * HH;
    int* rowp  = (int*)(ed + NN * HH);                  // N+1
    int* esrc  = rowp + NN + 1;                         // E + 64 pad
    float* scp1 = (float*)(esrc + EG + 64);             // 4*N
    float* scp2 = scp1 + 4 * NN;                        // 4*N
    int* sel1  = (int*)(scp2 + 4 * NN);                 // N
    float* w12 = (float*)(sel1 + NN);                   // C
    float* T   = w12 + CC;                              // 256*64
    float* Wc  = T + CC * 64;                           // 256*64
    float* bc2 = Wc + CC * 64;                          // 64
    float* bcv = bc2 + 64;                              // 64
    float* partial = bcv + 64;                          // BG*4*CC

    // ---- prep + conversions + CSR build ----
    prep<<<66, 256, 0, stream>>>(p1_tw, p2_sw, w12, p2_tw, c1w, p2_tb, T, bc2);
    conv_wpack<<<48, 256, 0, stream>>>(W1, W2, w1ph, w1pl, w2ph, w2pl);
    csr_build<<<BG, 1024, 0, stream>>>(src, dst, rowp, esrc);
    fold_W<<<65, 256, 0, stream>>>(p1_tw, T, p1_tb, bc2, c1b, Wc, bcv);

    // ---- GAT layer 1 ----
    gemm_mfma_attn_f32<<<NN / 32, 256, 0, stream>>>(x, w1ph, w1pl, z, FIN,
                                                    a_src1, a_dst1, es, ed);
    gat_lds<<<256, 1024, 0, stream>>>(z, rowp, esrc, es, ed, b1,
                                      nullptr, fhi, flo,
                                      nullptr, nullptr, nullptr, nullptr);

    // ---- GAT layer 2 ----
    gemm_mfma_attn<<<NN / 32, 256, 0, stream>>>(fhi, flo, w2ph, w2pl, z, CC,
                                                a_src2, a_dst2, es, ed);
    gat_lds<<<256, 1024, 0, stream>>>(z, rowp, esrc, es, ed, b2,
                                      featF, nullptr, nullptr,
                                      p1_sw, w12, scp1, scp2);

    // ---- pooling + folded head ----
    topk_ranks<<<BG * 4, 128, 0, stream>>>(scp1, sel1, KP1);
    topk2_mean<<<BG * 4, 256, 0, stream>>>(scp2, sel1, featF, partial);
    head_k<<<BG, 256, 0, stream>>>(partial, Wc, bcv, c2w, c2b, out);
}

// Round 15
// 304.684 us; speedup vs baseline: 1.2441x; 1.2441x over previous
//
#include <hip/hip_runtime.h>
#include <hip/hip_bf16.h>
#include <math.h>

// ---------------- problem constants ----------------
constexpr int NN  = 32768;   // nodes
constexpr int BG  = 64;      // graphs
constexpr int NPG = 512;     // nodes per graph
constexpr int EG  = 524288;  // edges
constexpr int EPG = EG / BG; // 8192 edges per graph
constexpr int HH  = 4;       // heads
constexpr int FH  = 64;      // per-head dim
constexpr int CC  = 256;     // H*Fh
constexpr int FIN = 128;
constexpr int KP1 = 256;     // pool1 k
constexpr int KP2 = 128;     // pool2 k
constexpr int NS  = 4;       // register edge slots: fast path deg <= 64

typedef __attribute__((ext_vector_type(8))) short short8;  // 8 bf16 = 4 VGPRs
typedef __attribute__((ext_vector_type(4))) float f32x4;

__device__ inline float leaky02(float v) { return v > 0.0f ? v : 0.2f * v; }

__device__ inline unsigned short f2bf(float v) {
    __hip_bfloat16 h = __float2bfloat16(v);
    return *(unsigned short*)&h;
}
__device__ inline float bf2f(unsigned short u) {
    __hip_bfloat16 h;
    *(unsigned short*)&h = u;
    return __bfloat162float(h);
}
__device__ inline void split2(float v, unsigned short& hi, unsigned short& lo) {
    hi = f2bf(v);
    lo = f2bf(v - bf2f(hi));
}
// split 8 consecutive floats into hi/lo bf16 fragments (A-operand order)
__device__ inline void split8(const float* p, short8& hi, short8& lo) {
    const float4 f0 = *(const float4*)p;
    const float4 f1 = *(const float4*)(p + 4);
    unsigned short h, l;
    split2(f0.x, h, l); hi[0] = (short)h; lo[0] = (short)l;
    split2(f0.y, h, l); hi[1] = (short)h; lo[1] = (short)l;
    split2(f0.z, h, l); hi[2] = (short)h; lo[2] = (short)l;
    split2(f0.w, h, l); hi[3] = (short)h; lo[3] = (short)l;
    split2(f1.x, h, l); hi[4] = (short)h; lo[4] = (short)l;
    split2(f1.y, h, l); hi[5] = (short)h; lo[5] = (short)l;
    split2(f1.z, h, l); hi[6] = (short)h; lo[6] = (short)l;
    split2(f1.w, h, l); hi[7] = (short)h; lo[7] = (short)l;
}

// ---------------- W pack: fp32 -> FRAGMENT-PACKED split bf16 --------------
// Packed layout: [nt (16 cols)][kg (32 k)][lane l][j]:
//   n = nt*16 + (l&15), k = kg*32 + (l>>4)*8 + j
__global__ __launch_bounds__(256) void conv_wpack(const float* __restrict__ W1,
                                                  const float* __restrict__ W2,
                                                  unsigned short* __restrict__ w1ph,
                                                  unsigned short* __restrict__ w1pl,
                                                  unsigned short* __restrict__ w2ph,
                                                  unsigned short* __restrict__ w2pl) {
    int idx = blockIdx.x * 256 + threadIdx.x;      // 0 .. 12287
    if (idx < 4096) {                              // W1: 16 nt x 4 kg x 64 l
        const int nt = idx >> 8, rem = idx & 255;
        const int kg = rem >> 6, l = rem & 63;
        const int n = nt * 16 + (l & 15);
        const int kb = kg * 32 + (l >> 4) * 8;
        unsigned short h[8], lo[8];
#pragma unroll
        for (int j = 0; j < 8; ++j) split2(W1[(kb + j) * CC + n], h[j], lo[j]);
#pragma unroll
        for (int j = 0; j < 8; ++j) {
            w1ph[(size_t)idx * 8 + j] = h[j];
            w1pl[(size_t)idx * 8 + j] = lo[j];
        }
    } else if (idx < 12288) {                      // W2: 16 nt x 8 kg x 64 l
        const int i2 = idx - 4096;
        const int nt = i2 >> 9, rem = i2 & 511;
        const int kg = rem >> 6, l = rem & 63;
        const int n = nt * 16 + (l & 15);
        const int kb = kg * 32 + (l >> 4) * 8;
        unsigned short h[8], lo[8];
#pragma unroll
        for (int j = 0; j < 8; ++j) split2(W2[(kb + j) * CC + n], h[j], lo[j]);
#pragma unroll
        for (int j = 0; j < 8; ++j) {
            w2ph[(size_t)i2 * 8 + j] = h[j];
            w2pl[(size_t)i2 * 8 + j] = lo[j];
        }
    }
}

// ---------------- MFMA GEMM (layer 2): A = split-bf16 pair ----------------
__global__ __launch_bounds__(256, 4) void gemm_mfma_attn(
        const unsigned short* __restrict__ Ahi, const unsigned short* __restrict__ Alo,
        const unsigned short* __restrict__ Bph, const unsigned short* __restrict__ Bpl,
        float* __restrict__ Cm, int K,
        const float* __restrict__ a_src, const float* __restrict__ a_dst,
        float* __restrict__ es, float* __restrict__ ed) {
    const int t = threadIdx.x;
    const int w = t >> 6;          // wave = col strip = head
    const int l = t & 63;
    const int bx   = blockIdx.x;               // 0..1023
    const int xcd  = bx & 7;
    const int slot = bx >> 3;                  // 0..127
    const int gph  = xcd + ((slot >> 4) << 3); // graph
    const int row0 = gph * NPG + ((slot & 15) << 5);
    const int m = l & 15;
    const int q = l >> 4;
    const int ncol0 = w * 64;
    const int KG = K >> 5;

    const unsigned short* aH0 = Ahi + (size_t)(row0 + m) * K + q * 8;
    const unsigned short* aL0 = Alo + (size_t)(row0 + m) * K + q * 8;
    const unsigned short* aH1 = aH0 + (size_t)16 * K;
    const unsigned short* aL1 = aL0 + (size_t)16 * K;

    f32x4 acc0[4], acc1[4];
#pragma unroll
    for (int c = 0; c < 4; ++c) {
        acc0[c] = (f32x4){0.f, 0.f, 0.f, 0.f};
        acc1[c] = (f32x4){0.f, 0.f, 0.f, 0.f};
    }

    for (int kg = 0; kg < KG; ++kg) {
        const int ko = kg * 32;
        short8 ah0 = *(const short8*)(aH0 + ko);
        short8 al0 = *(const short8*)(aL0 + ko);
        short8 ah1 = *(const short8*)(aH1 + ko);
        short8 al1 = *(const short8*)(aL1 + ko);
#pragma unroll
        for (int c = 0; c < 4; ++c) {
            const int nt = (w << 2) + c;
            const size_t boff = ((size_t)(nt * KG + kg) * 64 + l) * 8;
            short8 bh = *(const short8*)(Bph + boff);
            short8 bl = *(const short8*)(Bpl + boff);
            acc0[c] = __builtin_amdgcn_mfma_f32_16x16x32_bf16(ah0, bh, acc0[c], 0, 0, 0);
            acc0[c] = __builtin_amdgcn_mfma_f32_16x16x32_bf16(ah0, bl, acc0[c], 0, 0, 0);
            acc0[c] = __builtin_amdgcn_mfma_f32_16x16x32_bf16(al0, bh, acc0[c], 0, 0, 0);
            acc1[c] = __builtin_amdgcn_mfma_f32_16x16x32_bf16(ah1, bh, acc1[c], 0, 0, 0);
            acc1[c] = __builtin_amdgcn_mfma_f32_16x16x32_bf16(ah1, bl, acc1[c], 0, 0, 0);
            acc1[c] = __builtin_amdgcn_mfma_f32_16x16x32_bf16(al1, bh, acc1[c], 0, 0, 0);
        }
    }

#pragma unroll
    for (int c = 0; c < 4; ++c)
#pragma unroll
        for (int r = 0; r < 4; ++r) {
            Cm[(size_t)(row0 + q * 4 + r) * CC + ncol0 + c * 16 + m] = acc0[c][r];
            Cm[(size_t)(row0 + 16 + q * 4 + r) * CC + ncol0 + c * 16 + m] = acc1[c][r];
        }

    float asv[4], adv[4];
#pragma unroll
    for (int c = 0; c < 4; ++c) {
        asv[c] = a_src[ncol0 + c * 16 + m];
        adv[c] = a_dst[ncol0 + c * 16 + m];
    }
#pragma unroll
    for (int r = 0; r < 4; ++r) {
        float ps0 = 0.f, pd0 = 0.f, ps1 = 0.f, pd1 = 0.f;
#pragma unroll
        for (int c = 0; c < 4; ++c) {
            ps0 = fmaf(acc0[c][r], asv[c], ps0);
            pd0 = fmaf(acc0[c][r], adv[c], pd0);
            ps1 = fmaf(acc1[c][r], asv[c], ps1);
            pd1 = fmaf(acc1[c][r], adv[c], pd1);
        }
#pragma unroll
        for (int o = 8; o >= 1; o >>= 1) {
            ps0 += __shfl_down(ps0, o, 16);
            pd0 += __shfl_down(pd0, o, 16);
            ps1 += __shfl_down(ps1, o, 16);
            pd1 += __shfl_down(pd1, o, 16);
        }
        if (m == 0) {
            es[(row0 + q * 4 + r) * HH + w] = ps0;
            ed[(row0 + q * 4 + r) * HH + w] = pd0;
            es[(row0 + 16 + q * 4 + r) * HH + w] = ps1;
            ed[(row0 + 16 + q * 4 + r) * HH + w] = pd1;
        }
    }
}

// ---------------- MFMA GEMM (layer 1): A = fp32, split in-register --------
__global__ __launch_bounds__(256, 4) void gemm_mfma_attn_f32(
        const float* __restrict__ Af,
        const unsigned short* __restrict__ Bph, const unsigned short* __restrict__ Bpl,
        float* __restrict__ Cm, int K,
        const float* __restrict__ a_src, const float* __restrict__ a_dst,
        float* __restrict__ es, float* __restrict__ ed) {
    const int t = threadIdx.x;
    const int w = t >> 6;
    const int l = t & 63;
    const int bx   = blockIdx.x;
    const int xcd  = bx & 7;
    const int slot = bx >> 3;
    const int gph  = xcd + ((slot >> 4) << 3);
    const int row0 = gph * NPG + ((slot & 15) << 5);
    const int m = l & 15;
    const int q = l >> 4;
    const int ncol0 = w * 64;
    const int KG = K >> 5;

    const float* aF0 = Af + (size_t)(row0 + m) * K + q * 8;
    const float* aF1 = aF0 + (size_t)16 * K;

    f32x4 acc0[4], acc1[4];
#pragma unroll
    for (int c = 0; c < 4; ++c) {
        acc0[c] = (f32x4){0.f, 0.f, 0.f, 0.f};
        acc1[c] = (f32x4){0.f, 0.f, 0.f, 0.f};
    }

    for (int kg = 0; kg < KG; ++kg) {
        const int ko = kg * 32;
        short8 ah0, al0, ah1, al1;
        split8(aF0 + ko, ah0, al0);
        split8(aF1 + ko, ah1, al1);
#pragma unroll
        for (int c = 0; c < 4; ++c) {
            const int nt = (w << 2) + c;
            const size_t boff = ((size_t)(nt * KG + kg) * 64 + l) * 8;
            short8 bh = *(const short8*)(Bph + boff);
            short8 bl = *(const short8*)(Bpl + boff);
            acc0[c] = __builtin_amdgcn_mfma_f32_16x16x32_bf16(ah0, bh, acc0[c], 0, 0, 0);
            acc0[c] = __builtin_amdgcn_mfma_f32_16x16x32_bf16(ah0, bl, acc0[c], 0, 0, 0);
            acc0[c] = __builtin_amdgcn_mfma_f32_16x16x32_bf16(al0, bh, acc0[c], 0, 0, 0);
            acc1[c] = __builtin_amdgcn_mfma_f32_16x16x32_bf16(ah1, bh, acc1[c], 0, 0, 0);
            acc1[c] = __builtin_amdgcn_mfma_f32_16x16x32_bf16(ah1, bl, acc1[c], 0, 0, 0);
            acc1[c] = __builtin_amdgcn_mfma_f32_16x16x32_bf16(al1, bh, acc1[c], 0, 0, 0);
        }
    }

#pragma unroll
    for (int c = 0; c < 4; ++c)
#pragma unroll
        for (int r = 0; r < 4; ++r) {
            Cm[(size_t)(row0 + q * 4 + r) * CC + ncol0 + c * 16 + m] = acc0[c][r];
            Cm[(size_t)(row0 + 16 + q * 4 + r) * CC + ncol0 + c * 16 + m] = acc1[c][r];
        }

    float asv[4], adv[4];
#pragma unroll
    for (int c = 0; c < 4; ++c) {
        asv[c] = a_src[ncol0 + c * 16 + m];
        adv[c] = a_dst[ncol0 + c * 16 + m];
    }
#pragma unroll
    for (int r = 0; r < 4; ++r) {
        float ps0 = 0.f, pd0 = 0.f, ps1 = 0.f, pd1 = 0.f;
#pragma unroll
        for (int c = 0; c < 4; ++c) {
            ps0 = fmaf(acc0[c][r], asv[c], ps0);
            pd0 = fmaf(acc0[c][r], adv[c], pd0);
            ps1 = fmaf(acc1[c][r], asv[c], ps1);
            pd1 = fmaf(acc1[c][r], adv[c], pd1);
        }
#pragma unroll
        for (int o = 8; o >= 1; o >>= 1) {
            ps0 += __shfl_down(ps0, o, 16);
            pd0 += __shfl_down(pd0, o, 16);
            ps1 += __shfl_down(ps1, o, 16);
            pd1 += __shfl_down(pd1, o, 16);
        }
        if (m == 0) {
            es[(row0 + q * 4 + r) * HH + w] = ps0;
            ed[(row0 + q * 4 + r) * HH + w] = pd0;
            es[(row0 + 16 + q * 4 + r) * HH + w] = ps1;
            ed[(row0 + 16 + q * 4 + r) * HH + w] = pd1;
        }
    }
}

// ---------------- prep: w12 + T = tw2@c1w + bc2 = tb2@c1w ------------------
// block 0: w12/b12. blocks 1..64: T rows (4/block). block 65: bc2.
__global__ __launch_bounds__(256) void prep(const float* __restrict__ tw1,
                                            const float* __restrict__ sw2,
                                            const float* __restrict__ tb1,
                                            const float* __restrict__ sb2,
                                            float* __restrict__ w12,
                                            float* __restrict__ b12,
                                            const float* __restrict__ tw2,
                                            const float* __restrict__ c1w,
                                            const float* __restrict__ tb2,
                                            float* __restrict__ T,
                                            float* __restrict__ bc2) {
    const int b = blockIdx.x;
    const int t = threadIdx.x;
    if (b == 0) {
        float s = 0.0f;
        for (int o = 0; o < CC; ++o) s += tw1[t * CC + o] * sw2[o];
        w12[t] = s;
        if (t == 0) {
            float bb = 0.0f;
            for (int o = 0; o < CC; ++o) bb += tb1[o] * sw2[o];
            *b12 = bb + sb2[0];
        }
    } else if (b < 65) {
        const int r = (b - 1) * 4 + (t >> 6);
        const int cth = t & 63;
        float s = 0.0f;
        for (int j = 0; j < CC; ++j) s = fmaf(tw2[r * CC + j], c1w[j * 64 + cth], s);
        T[r * 64 + cth] = s;
    } else if (t < 64) {
        float s = 0.0f;
        for (int j = 0; j < CC; ++j) s = fmaf(tb2[j], c1w[j * 64 + t], s);
        bc2[t] = s;
    }
}

// ---------------- fold_W: Wc = tw1@T, bc = tb1@T + bc2 + c1b --------------
__global__ __launch_bounds__(256) void fold_W(const float* __restrict__ tw1,
                                              const float* __restrict__ T,
                                              const float* __restrict__ tb1,
                                              const float* __restrict__ bc2,
                                              const float* __restrict__ c1b,
                                              float* __restrict__ Wc,
                                              float* __restrict__ bc) {
    const int b = blockIdx.x;
    const int t = threadIdx.x;
    if (b < 64) {
        const int r = b * 4 + (t >> 6);
        const int cth = t & 63;
        float s = 0.0f;
        for (int j = 0; j < CC; ++j) s = fmaf(tw1[r * CC + j], T[j * 64 + cth], s);
        Wc[r * 64 + cth] = s;
    } else if (t < 64) {
        float s = 0.0f;
        for (int j = 0; j < CC; ++j) s = fmaf(tb1[j], T[j * 64 + t], s);
        bc[t] = s + bc2[t] + c1b[t];
    }
}

// ---------------- single-kernel CSR build: one block per graph ------------
__global__ __launch_bounds__(1024) void csr_build(const int* __restrict__ src,
                                                  const int* __restrict__ dst,
                                                  int* __restrict__ rowp,
                                                  int* __restrict__ esrc) {
    __shared__ int lcnt[NPG];
    __shared__ int lofs[NPG];
    const int g = blockIdx.x;
    const int t = threadIdx.x;
    const int ebase = g * EPG;
    const int nbase = g * NPG;
    if (t < NPG) lcnt[t] = 0;
    __syncthreads();
    int ds[EPG / 1024];
#pragma unroll
    for (int j = 0; j < EPG / 1024; ++j) {
        ds[j] = dst[ebase + t + 1024 * j] - nbase;
        atomicAdd(&lcnt[ds[j]], 1);
    }
    __syncthreads();
    if (t < NPG) lofs[t] = lcnt[t];
    __syncthreads();
    for (int o = 1; o < NPG; o <<= 1) {
        int v = 0;
        if (t < NPG && t >= o) v = lofs[t - o];
        __syncthreads();
        if (t < NPG) lofs[t] += v;
        __syncthreads();
    }
    if (t < NPG) {
        int ex = lofs[t] - lcnt[t];
        rowp[nbase + t] = ebase + ex;
        lcnt[t] = ex;
    }
    if (g == BG - 1 && t == 0) rowp[NN] = EG;
    __syncthreads();
#pragma unroll
    for (int j = 0; j < EPG / 1024; ++j) {
        int p = atomicAdd(&lcnt[ds[j]], 1);
        esrc[ebase + p] = src[ebase + t + 1024 * j];
    }
}

// ---------------- fused GAT edge stage: softmax + aggregate + ELU ----------
__global__ __launch_bounds__(256) void gat_edge(const float* __restrict__ z,
                                                const int* __restrict__ rowp,
                                                const int* __restrict__ esrc,
                                                const float* __restrict__ es,
                                                const float* __restrict__ ed,
                                                const float* __restrict__ bias,
                                                float* __restrict__ out,
                                                unsigned short* __restrict__ outh,
                                                unsigned short* __restrict__ outl,
                                                const float* __restrict__ sw1,
                                                const float* __restrict__ sb1,
                                                const float* __restrict__ w12,
                                                const float* __restrict__ b12,
                                                float* __restrict__ sc1,
                                                float* __restrict__ sc2) {
    const int w = threadIdx.x >> 6;
    const int l = threadIdx.x & 63;
    const int b    = blockIdx.x;              // 0..8191
    const int xcd  = b & 7;
    const int slot = b >> 3;                  // 0..1023
    const int gph  = xcd + ((slot >> 7) << 3);
    const int d    = gph * NPG + ((slot & 127) << 2) + w;

    const int h  = l & 3;
    const int ei = l >> 2;
    const int h2 = l >> 4;
    const int beg = rowp[d];
    const int deg = rowp[d + 1] - beg;

    const float4 zv = *(const float4*)(z + (size_t)d * CC + 4 * l);
    float4 acc;

    if (deg <= 16 * NS) {
        const float edh = ed[d * HH + h];
        int   sidx[NS];
        float v[NS];
#pragma unroll
        for (int j = 0; j < NS; ++j) { sidx[j] = d; v[j] = 0.0f; }
        float vmax = -INFINITY, eself = 0.0f;
        float vself = 0.0f;
        if (ei == 0) {
            vself = leaky02(es[d * HH + h] + edh);
            vmax = vself;
        }
#pragma unroll
        for (int j = 0; j < NS; ++j) {
            int i = ei + 16 * j;
            if (i < deg) {
                sidx[j] = esrc[beg + i];
                v[j] = leaky02(es[sidx[j] * HH + h] + edh);
                vmax = fmaxf(vmax, v[j]);
            }
        }
#pragma unroll
        for (int o = 4; o <= 32; o <<= 1) vmax = fmaxf(vmax, __shfl_xor(vmax, o));
        float dsum = 0.0f;
#pragma unroll
        for (int j = 0; j < NS; ++j) {
            int i = ei + 16 * j;
            if (i < deg) { v[j] = __expf(v[j] - vmax); dsum += v[j]; }
        }
        if (ei == 0) { eself = __expf(vself - vmax); dsum += eself; }
#pragma unroll
        for (int o = 4; o <= 32; o <<= 1) dsum += __shfl_xor(dsum, o);
        const float inv = 1.0f / (dsum + 1e-16f);
#pragma unroll
        for (int j = 0; j < NS; ++j) v[j] *= inv;   // normalized alpha (0 = pad)
        eself *= inv;

        float aself = __shfl(eself, h2);
        acc = make_float4(aself * zv.x, aself * zv.y, aself * zv.z, aself * zv.w);
#pragma unroll
        for (int jj = 0; jj < 2 * NS; ++jj) {
            if (8 * jj < deg) {
                const int j = jj >> 1;
                const int lb = 32 * (jj & 1);
#pragma unroll
                for (int s = 0; s < 8; ++s) {
                    int   srcn = __builtin_amdgcn_readlane(sidx[j], lb + 4 * s);
                    float a    = __shfl(v[j], lb + 4 * s + h2);
                    const float4 zs = *(const float4*)(z + (size_t)srcn * CC + 4 * l);
                    acc.x = fmaf(a, zs.x, acc.x);
                    acc.y = fmaf(a, zs.y, acc.y);
                    acc.z = fmaf(a, zs.z, acc.z);
                    acc.w = fmaf(a, zs.w, acc.w);
                }
            }
        }
    } else {
        const float edh = ed[d * HH + h];
        float vmax = (ei == 0) ? leaky02(es[d * HH + h] + edh) : -INFINITY;
        for (int i = ei; i < deg; i += 16)
            vmax = fmaxf(vmax, leaky02(es[esrc[beg + i] * HH + h] + edh));
#pragma unroll
        for (int o = 4; o <= 32; o <<= 1) vmax = fmaxf(vmax, __shfl_xor(vmax, o));
        float dsum = (ei == 0) ? __expf(leaky02(es[d * HH + h] + edh) - vmax) : 0.0f;
        for (int i = ei; i < deg; i += 16)
            dsum += __expf(leaky02(es[esrc[beg + i] * HH + h] + edh) - vmax);
#pragma unroll
        for (int o = 4; o <= 32; o <<= 1) dsum += __shfl_xor(dsum, o);
        const float inv = 1.0f / (dsum + 1e-16f);

        const float vmaxc = __shfl(vmax, h2);
        const float invc  = __shfl(inv,  h2);
        const float edh4  = ed[d * HH + h2];
        float a0 = __expf(leaky02(es[d * HH + h2] + edh4) - vmaxc) * invc;
        acc = make_float4(a0 * zv.x, a0 * zv.y, a0 * zv.z, a0 * zv.w);
        for (int i = 0; i < deg; ++i) {
            int srcn = esrc[beg + i];
            float a = __expf(leaky02(es[srcn * HH + h2] + edh4) - vmaxc) * invc;
            float4 zs = *(const float4*)(z + (size_t)srcn * CC + 4 * l);
            acc.x = fmaf(a, zs.x, acc.x);
            acc.y = fmaf(a, zs.y, acc.y);
            acc.z = fmaf(a, zs.z, acc.z);
            acc.w = fmaf(a, zs.w, acc.w);
        }
    }

    const float4 bv = *(const float4*)(bias + 4 * l);
    float4 o;
    o.x = acc.x + bv.x; o.x = o.x > 0.0f ? o.x : expm1f(o.x);
    o.y = acc.y + bv.y; o.y = o.y > 0.0f ? o.y : expm1f(o.y);
    o.z = acc.z + bv.z; o.z = o.z > 0.0f ? o.z : expm1f(o.z);
    o.w = acc.w + bv.w; o.w = o.w > 0.0f ? o.w : expm1f(o.w);

    if (out) *(float4*)(out + (size_t)d * CC + 4 * l) = o;
    if (outh) {
        ushort4 uh, ul;
        split2(o.x, uh.x, ul.x);
        split2(o.y, uh.y, ul.y);
        split2(o.z, uh.z, ul.z);
        split2(o.w, uh.w, ul.w);
        ((ushort4*)outh)[(size_t)d * 64 + l] = uh;
        ((ushort4*)outl)[(size_t)d * 64 + l] = ul;
    }

    if (sc1) {
        const float4 s1 = *(const float4*)(sw1 + 4 * l);
        const float4 s2 = *(const float4*)(w12 + 4 * l);
        float r1 = o.x * s1.x + o.y * s1.y + o.z * s1.z + o.w * s1.w;
        float r2 = o.x * s2.x + o.y * s2.y + o.z * s2.z + o.w * s2.w;
#pragma unroll
        for (int off = 32; off >= 1; off >>= 1) {
            r1 += __shfl_xor(r1, off);
            r2 += __shfl_xor(r2, off);
        }
        if (l == 0) {
            sc1[d] = r1 + sb1[0];
            sc2[d] = r2 + b12[0];
        }
    }
}

// ---------------- top-k1 rank counting, 4 blocks/graph --------------------
__global__ __launch_bounds__(128) void topk_ranks(const float* __restrict__ sc,
                                                  int* __restrict__ sel, int k) {
    __shared__ float s4[NPG];
    const int b = blockIdx.x;
    const int g = b >> 2;
    const int p = b & 3;
    const int t = threadIdx.x;   // 0..127
    float4 v = *(const float4*)(sc + (size_t)g * NPG + t * 4);
    *(float4*)(s4 + t * 4) = v;
    __syncthreads();
    const int n = p * 128 + t;
    const float my = s4[n];
    int rank = 0;
#pragma unroll 16
    for (int j4 = 0; j4 < NPG / 4; ++j4) {
        const float4 sv = *(const float4*)(s4 + j4 * 4);
        const int jb = j4 * 4;
        rank += (sv.x > my) || (sv.x == my && (jb + 0) < n);
        rank += (sv.y > my) || (sv.y == my && (jb + 1) < n);
        rank += (sv.z > my) || (sv.z == my && (jb + 2) < n);
        rank += (sv.w > my) || (sv.w == my && (jb + 3) < n);
    }
    sel[(size_t)g * NPG + n] = (rank < k);
}

// ---------------- fused top-k2 + masked partial mean, 4 blocks/graph ------
__global__ __launch_bounds__(256) void topk2_mean(const float* __restrict__ sc2,
                                                  const int* __restrict__ sel1,
                                                  const float* __restrict__ feat,
                                                  float* __restrict__ partial) {
    __shared__ float s4[NPG];
    __shared__ int keep[128];
    __shared__ float vbuf[4][CC];
    const int b = blockIdx.x;    // 0..255
    const int g = b >> 2, p = b & 3;
    const int t = threadIdx.x;   // 0..255
    if (t < 128) {
        float4 v = *(const float4*)(sc2 + (size_t)g * NPG + t * 4);
        int4 mk = *(const int4*)(sel1 + (size_t)g * NPG + t * 4);
        v.x = mk.x ? v.x : -INFINITY;
        v.y = mk.y ? v.y : -INFINITY;
        v.z = mk.z ? v.z : -INFINITY;
        v.w = mk.w ? v.w : -INFINITY;
        *(float4*)(s4 + t * 4) = v;
    }
    __syncthreads();
    if (t < 128) {
        const int n = p * 128 + t;
        const float my = s4[n];
        int rank = 0;
#pragma unroll 16
        for (int j4 = 0; j4 < NPG / 4; ++j4) {
            const float4 sv = *(const float4*)(s4 + j4 * 4);
            const int jb = j4 * 4;
            rank += (sv.x > my) || (sv.x == my && (jb + 0) < n);
            rank += (sv.y > my) || (sv.y == my && (jb + 1) < n);
            rank += (sv.z > my) || (sv.z == my && (jb + 2) < n);
            rank += (sv.w > my) || (sv.w == my && (jb + 3) < n);
        }
        keep[t] = (rank < KP2) && sel1[(size_t)g * NPG + n];
    }
    __syncthreads();
    const int r = t >> 6, c4 = t & 63;
    float4 acc = make_float4(0.f, 0.f, 0.f, 0.f);
    const float4* f4 = (const float4*)(feat + ((size_t)g * NPG + p * 128) * CC);
    for (int j = r; j < 128; j += 4) {
        if (keep[j]) {
            float4 v = f4[j * 64 + c4];
            acc.x += v.x; acc.y += v.y; acc.z += v.z; acc.w += v.w;
        }
    }
    vbuf[r][c4 * 4 + 0] = acc.x;
    vbuf[r][c4 * 4 + 1] = acc.y;
    vbuf[r][c4 * 4 + 2] = acc.z;
    vbuf[r][c4 * 4 + 3] = acc.w;
    __syncthreads();
    partial[(size_t)(g * 4 + p) * CC + t] =
        vbuf[0][t] + vbuf[1][t] + vbuf[2][t] + vbuf[3][t];
}

// ---------------- folded head ----------------
__global__ __launch_bounds__(256) void head_k(const float* __restrict__ partial,
                                              const float* __restrict__ Wc,
                                              const float* __restrict__ bc,
                                              const float* __restrict__ c2w,
                                              const float* __restrict__ c2b,
                                              float* __restrict__ out) {
    __shared__ float v0[CC];
    __shared__ float part[4][64];
    __shared__ float v2[64];
    const int g = blockIdx.x;
    const int i = threadIdx.x;
    float tsum = partial[(size_t)(g * 4 + 0) * CC + i] +
                 partial[(size_t)(g * 4 + 1) * CC + i] +
                 partial[(size_t)(g * 4 + 2) * CC + i] +
                 partial[(size_t)(g * 4 + 3) * CC + i];
    v0[i] = tsum * (1.0f / KP2);
    __syncthreads();
    {
        const int q = i >> 6, cth = i & 63;
        float p = 0.0f;
        for (int j = q * 64; j < q * 64 + 64; ++j)
            p = fmaf(v0[j], Wc[j * 64 + cth], p);
        part[q][cth] = p;
    }
    __syncthreads();
    if (i < 64) {
        float u = bc[i];
#pragma unroll
        for (int q = 0; q < 4; ++q) u += part[q][i];
        v2[i] = fmaxf(u, 0.0f);
    }
    __syncthreads();
    if (i < 2) {
        float o = c2b[i];
        for (int j = 0; j < 64; ++j) o = fmaf(v2[j], c2w[j * 2 + i], o);
        part[0][i] = o;
    }
    __syncthreads();
    if (i == 0) {
        float a = part[0][0], bq = part[0][1];
        float mx = fmaxf(a, bq);
        float lse = mx + logf(expf(a - mx) + expf(bq - mx));
        out[g * 2 + 0] = a - lse;
        out[g * 2 + 1] = bq - lse;
    }
}

// ---------------- launcher ----------------
extern "C" void kernel_launch(void* const* d_in, const int* in_sizes, int n_in,
                              void* d_out, int out_size, void* d_ws, size_t ws_size,
                              hipStream_t stream) {
    const float* x      = (const float*)d_in[0];
    const int*   ei     = (const int*)d_in[1];
    const int*   src    = ei;
    const int*   dst    = ei + EG;
    const float* W1     = (const float*)d_in[3];
    const float* a_src1 = (const float*)d_in[4];
    const float* a_dst1 = (const float*)d_in[5];
    const float* b1     = (const float*)d_in[6];
    const float* W2     = (const float*)d_in[7];
    const float* a_src2 = (const float*)d_in[8];
    const float* a_dst2 = (const float*)d_in[9];
    const float* b2     = (const float*)d_in[10];
    const float* p1_sw  = (const float*)d_in[11];
    const float* p1_sb  = (const float*)d_in[12];
    const float* p1_tw  = (const float*)d_in[13];
    const float* p1_tb  = (const float*)d_in[14];
    const float* p2_sw  = (const float*)d_in[15];
    const float* p2_sb  = (const float*)d_in[16];
    const float* p2_tw  = (const float*)d_in[17];
    const float* p2_tb  = (const float*)d_in[18];
    const float* c1w    = (const float*)d_in[19];
    const float* c1b    = (const float*)d_in[20];
    const float* c2w    = (const float*)d_in[21];
    const float* c2b    = (const float*)d_in[22];
    float* out = (float*)d_out;

    // workspace layout
    float* ws = (float*)d_ws;
    float* z = ws;                                      // NN*CC floats
    float* fregion = z + (size_t)NN * CC;               // NN*CC floats
    unsigned short* fhi = (unsigned short*)fregion;     //   phase 1: fhi/flo bf16
    unsigned short* flo = fhi + (size_t)NN * CC;
    float* featF = fregion;                             //   phase 2: fp32 feat (alias)
    float* wsp = fregion + (size_t)NN * CC;
    unsigned short* w1ph = (unsigned short*)wsp;        // 256*128 packed
    unsigned short* w1pl = w1ph + 256 * FIN;
    unsigned short* w2ph = w1pl + 256 * FIN;            // 256*256 packed
    unsigned short* w2pl = w2ph + 256 * CC;
    float* es  = (float*)(w2pl + 256 * CC);             // N*H
    float* ed  = es + NN * HH;
    int* rowp  = (int*)(ed + NN * HH);                  // N+1
    int* esrc  = rowp + NN + 1;                         // E
    float* sc1 = (float*)(esrc + EG);                   // N
    float* sc2 = sc1 + NN;                              // N
    int* sel1  = (int*)(sc2 + NN);                      // N
    float* w12 = (float*)(sel1 + NN);                   // C
    float* b12 = w12 + CC;                              // 1 (padded 64)
    float* T   = b12 + 64;                              // 256*64
    float* Wc  = T + CC * 64;                           // 256*64
    float* bc2 = Wc + CC * 64;                          // 64
    float* bcv = bc2 + 64;                              // 64
    float* partial = bcv + 64;                          // BG*4*CC

    // ---- prep + conversions + CSR build ----
    prep<<<66, 256, 0, stream>>>(p1_tw, p2_sw, p1_tb, p2_sb, w12, b12,
                                 p2_tw, c1w, p2_tb, T, bc2);
    conv_wpack<<<48, 256, 0, stream>>>(W1, W2, w1ph, w1pl, w2ph, w2pl);
    csr_build<<<BG, 1024, 0, stream>>>(src, dst, rowp, esrc);
    fold_W<<<65, 256, 0, stream>>>(p1_tw, T, p1_tb, bc2, c1b, Wc, bcv);

    // ---- GAT layer 1 (fp32 A split in-register) ----
    gemm_mfma_attn_f32<<<NN / 32, 256, 0, stream>>>(x, w1ph, w1pl, z, FIN,
                                                    a_src1, a_dst1, es, ed);
    gat_edge<<<NN / 4, 256, 0, stream>>>(z, rowp, esrc, es, ed, b1,
                                         nullptr, fhi, flo,
                                         nullptr, nullptr, nullptr, nullptr,
                                         nullptr, nullptr);

    // ---- GAT layer 2 ----
    gemm_mfma_attn<<<NN / 32, 256, 0, stream>>>(fhi, flo, w2ph, w2pl, z, CC,
                                                a_src2, a_dst2, es, ed);
    gat_edge<<<NN / 4, 256, 0, stream>>>(z, rowp, esrc, es, ed, b2,
                                         featF, nullptr, nullptr,
                                         p1_sw, p1_sb, w12, b12, sc1, sc2);

    // ---- pooling + folded head ----
    topk_ranks<<<BG * 4, 128, 0, stream>>>(sc1, sel1, KP1);
    topk2_mean<<<BG * 4, 256, 0, stream>>>(sc2, sel1, featF, partial);
    head_k<<<BG, 256, 0, stream>>>(partial, Wc, bcv, c2w, c2b, out);
}